// Round 10
// baseline (1143.975 us; speedup 1.0000x reference)
//
#include <hip/hip_runtime.h>
#include <math.h>

#define LQ 4096
#define DI 192
#define DS 16
#define NCHUNK 64

__device__ __forceinline__ float siluf_(float v) { return v / (1.f + __expf(-v)); }
__device__ __forceinline__ float softplusf_(float v) { return v > 20.f ? v : log1pf(__expf(v)); }

// 16-lane rotate-reduce step: x += row_ror<CTRL>(x). CTRL: 0x121+N-1 = row_ror:N.
template <int CTRL>
__device__ __forceinline__ float dpp_add16_(float x) {
    int y = __builtin_amdgcn_update_dpp(0, __float_as_int(x), CTRL, 0xf, 0xf, true);
    return x + __int_as_float(y);
}

// ---------------- K1: in_proj GEMM  xz[b,l,n] = sum_c x[b,c,l] * W[n,c] ----------------
// grid (L/64, 6, B), block 256. n-tile<192 -> xi_raw, else z.
__global__ __launch_bounds__(256) void k1_inproj(const float* __restrict__ x,
    const float* __restrict__ w, float* __restrict__ xi_raw, float* __restrict__ z)
{
    const int l0 = blockIdx.x * 64;
    const int n0 = blockIdx.y * 64;
    const int b  = blockIdx.z;
    __shared__ float xs[96 * 64];    // [c][l]
    __shared__ float wsT[96 * 68];   // [c][n], padded stride 68
    const int tid = threadIdx.x;
    for (int i = tid; i < 96 * 16; i += 256) {
        int c = i >> 4, lq = i & 15;
        *(float4*)&xs[c * 64 + lq * 4] =
            *(const float4*)&x[(b * 96 + c) * LQ + l0 + lq * 4];
    }
    for (int i = tid; i < 64 * 24; i += 256) {
        int n = i / 24, cq = i - n * 24;
        float4 v = *(const float4*)&w[(n0 + n) * 96 + cq * 4];
        wsT[(cq * 4 + 0) * 68 + n] = v.x;
        wsT[(cq * 4 + 1) * 68 + n] = v.y;
        wsT[(cq * 4 + 2) * 68 + n] = v.z;
        wsT[(cq * 4 + 3) * 68 + n] = v.w;
    }
    __syncthreads();
    const int tx = tid & 15;   // n quad
    const int ty = tid >> 4;   // l quad
    float acc[4][4];
#pragma unroll
    for (int i = 0; i < 4; ++i)
#pragma unroll
        for (int j = 0; j < 4; ++j) acc[i][j] = 0.f;
    for (int k = 0; k < 96; ++k) {
        float4 a  = *(const float4*)&xs[k * 64 + ty * 4];
        float4 bb = *(const float4*)&wsT[k * 68 + tx * 4];
        float av[4] = {a.x, a.y, a.z, a.w};
        float bv[4] = {bb.x, bb.y, bb.z, bb.w};
#pragma unroll
        for (int i = 0; i < 4; ++i)
#pragma unroll
            for (int j = 0; j < 4; ++j) acc[i][j] += av[i] * bv[j];
    }
    float* dst = (n0 < DI) ? xi_raw : z;
    const int nn0 = (n0 < DI) ? n0 : (n0 - DI);
#pragma unroll
    for (int i = 0; i < 4; ++i) {
        int l = l0 + ty * 4 + i;
        float4 v = make_float4(acc[i][0], acc[i][1], acc[i][2], acc[i][3]);
        *(float4*)&dst[(b * LQ + l) * DI + nn0 + tx * 4] = v;
    }
}

// ---------------- K2: causal depthwise conv1d + bias + SiLU ----------------
__global__ __launch_bounds__(256) void k2_conv1d(const float* __restrict__ xir,
    const float* __restrict__ cw, const float* __restrict__ cb, float* __restrict__ xi)
{
    int idx = blockIdx.x * 256 + threadIdx.x;       // b*L*DI total
    int d = idx % DI;
    int l = (idx / DI) & (LQ - 1);
    float4 wv = *(const float4*)&cw[d * 4];
    float wk[4] = {wv.x, wv.y, wv.z, wv.w};
    float acc = cb[d];
#pragma unroll
    for (int k = 0; k < 4; ++k) {
        int lp = l - 3 + k;
        if (lp >= 0) acc += wk[k] * xir[idx + (k - 3) * DI];
    }
    xi[idx] = siluf_(acc);
}

// ---------------- K3: x_dbl[b,l,n] = sum_k xi[b,l,k] * xw[n,k], n<38 ----------------
// grid (L/64, B). K staged in two halves (LDS < 64KB).
__global__ __launch_bounds__(256) void k3_xdbl(const float* __restrict__ xi,
    const float* __restrict__ xw, float* __restrict__ xdbl)
{
    const int l0 = blockIdx.x * 64;
    const int b  = blockIdx.y;
    __shared__ float sxiT[96 * 68];   // [k(half)][l]
    __shared__ float swx[38 * 196];   // [n][k], padded
    const int tid = threadIdx.x;
    for (int i = tid; i < 38 * 48; i += 256) {
        int n = i / 48, kq = i - n * 48;
        *(float4*)&swx[n * 196 + kq * 4] = *(const float4*)&xw[n * 192 + kq * 4];
    }
    const int lq = tid & 15, ng = tid >> 4;
    float acc[3][4];
#pragma unroll
    for (int p = 0; p < 3; ++p)
#pragma unroll
        for (int i = 0; i < 4; ++i) acc[p][i] = 0.f;
    for (int half = 0; half < 2; ++half) {
        __syncthreads();
        for (int i = tid; i < 64 * 24; i += 256) {
            int l = i / 24, kq = i - l * 24;
            float4 v = *(const float4*)&xi[(b * LQ + l0 + l) * DI + half * 96 + kq * 4];
            sxiT[(kq * 4 + 0) * 68 + l] = v.x;
            sxiT[(kq * 4 + 1) * 68 + l] = v.y;
            sxiT[(kq * 4 + 2) * 68 + l] = v.z;
            sxiT[(kq * 4 + 3) * 68 + l] = v.w;
        }
        __syncthreads();
#pragma unroll
        for (int pass = 0; pass < 3; ++pass) {
            int n = pass * 16 + ng;
            if (n >= 38) continue;
            for (int k = 0; k < 96; ++k) {
                float4 a = *(const float4*)&sxiT[k * 68 + lq * 4];
                float bv = swx[n * 196 + half * 96 + k];
                acc[pass][0] += a.x * bv;
                acc[pass][1] += a.y * bv;
                acc[pass][2] += a.z * bv;
                acc[pass][3] += a.w * bv;
            }
        }
    }
#pragma unroll
    for (int pass = 0; pass < 3; ++pass) {
        int n = pass * 16 + ng;
        if (n >= 38) continue;
#pragma unroll
        for (int i = 0; i < 4; ++i)
            xdbl[(b * LQ + l0 + lq * 4 + i) * 38 + n] = acc[pass][i];
    }
}

// ---------------- K4: scan pass A — per-chunk (prod dA, affine tail), h0 = 0 ----------------
// grid (NCHUNK, 12, B), block 256 = 16 d x 16 s
__global__ __launch_bounds__(256) void k4_scanA(
    const float* __restrict__ xdbl, const float* __restrict__ xi,
    const float* __restrict__ dtw, const float* __restrict__ dtb,
    const float* __restrict__ alog,
    float* __restrict__ cA, float* __restrict__ cB)
{
    const int ch = blockIdx.x, g = blockIdx.y, b = blockIdx.z;
    const int t0 = ch * 64, d0 = g * 16;
    __shared__ float sxd[64 * 40];
    __shared__ float sdt[1024], sxi[1024];
    __shared__ float sdtw[96], sdtb[16];
    const int tid = threadIdx.x;
    for (int i = tid; i < 64 * 38; i += 256) {
        int t = i / 38, cc = i - t * 38;
        sxd[t * 40 + cc] = xdbl[(b * LQ + t0 + t) * 38 + cc];
    }
    for (int i = tid; i < 1024; i += 256) {
        int t = i >> 4, j = i & 15;
        sxi[i] = xi[(b * LQ + t0 + t) * DI + d0 + j];
    }
    if (tid < 96) sdtw[tid] = dtw[d0 * 6 + tid];
    if (tid < 16) sdtb[tid] = dtb[d0 + tid];
    __syncthreads();
    for (int i = tid; i < 1024; i += 256) {
        int t = i >> 4, dl = i & 15;
        float acc = sdtb[dl];
#pragma unroll
        for (int r = 0; r < 6; ++r) acc += sxd[t * 40 + r] * sdtw[dl * 6 + r];
        sdt[i] = softplusf_(acc);
    }
    __syncthreads();
    const int s = tid & 15, dl = tid >> 4;
    const float Ads = -__expf(alog[(d0 + dl) * DS + s]);
    float a = 1.f, hb = 0.f;
#pragma unroll 4
    for (int t = 0; t < 64; ++t) {
        float dtv = sdt[t * 16 + dl];
        float dA = __expf(dtv * Ads);
        float dbx = dtv * sxd[t * 40 + 6 + s] * sxi[t * 16 + dl];
        a *= dA;
        hb = dA * hb + dbx;
    }
    int o = ((b * NCHUNK + ch) * DI + d0 + dl) * DS + s;
    cA[o] = a;
    cB[o] = hb;
}

// ---------------- K5: sequential combine over chunks -> h_init per chunk ----------------
__global__ __launch_bounds__(256) void k5_combine(const float* __restrict__ cA,
    const float* __restrict__ cB, float* __restrict__ hinit)
{
    int gid = blockIdx.x * 256 + threadIdx.x;   // 4*192*16 = 12288
    int b = gid / 3072;
    int rem = gid - b * 3072;
    int base = b * (NCHUNK * 3072) + rem;
    float h = 0.f;
#pragma unroll 8
    for (int c = 0; c < NCHUNK; ++c) {
        int o = base + c * 3072;
        hinit[o] = h;
        h = cA[o] * h + cB[o];
    }
}

// ---------------- K6: scan pass C — replay with true h_init, y = C.h, gate ----------------
// s-group reduction via DPP row_ror rotate-reduce (VALU), not shfl/LDS.
__global__ __launch_bounds__(256) void k6_scanC(
    const float* __restrict__ xdbl, const float* __restrict__ xi,
    const float* __restrict__ z, const float* __restrict__ dtw,
    const float* __restrict__ dtb, const float* __restrict__ alog,
    const float* __restrict__ Dp, const float* __restrict__ hinit,
    float* __restrict__ yg)
{
    const int ch = blockIdx.x, g = blockIdx.y, b = blockIdx.z;
    const int t0 = ch * 64, d0 = g * 16;
    __shared__ float sxd[64 * 40];
    __shared__ float sdt[1024], sxi[1024], szs[1024], sy[1024];
    __shared__ float sdtw[96], sdtb[16];
    const int tid = threadIdx.x;
    for (int i = tid; i < 64 * 38; i += 256) {
        int t = i / 38, cc = i - t * 38;
        sxd[t * 40 + cc] = xdbl[(b * LQ + t0 + t) * 38 + cc];
    }
    for (int i = tid; i < 1024; i += 256) {
        int t = i >> 4, j = i & 15;
        int row = b * LQ + t0 + t;
        sxi[i] = xi[row * DI + d0 + j];
        szs[i] = z[row * DI + d0 + j];
    }
    if (tid < 96) sdtw[tid] = dtw[d0 * 6 + tid];
    if (tid < 16) sdtb[tid] = dtb[d0 + tid];
    __syncthreads();
    for (int i = tid; i < 1024; i += 256) {
        int t = i >> 4, dl = i & 15;
        float acc = sdtb[dl];
#pragma unroll
        for (int r = 0; r < 6; ++r) acc += sxd[t * 40 + r] * sdtw[dl * 6 + r];
        sdt[i] = softplusf_(acc);
    }
    __syncthreads();
    const int s = tid & 15, dl = tid >> 4;
    const float Ads = -__expf(alog[(d0 + dl) * DS + s]);
    float h = hinit[((b * NCHUNK + ch) * DI + d0 + dl) * DS + s];
    for (int t = 0; t < 64; ++t) {
        float dtv = sdt[t * 16 + dl];
        float dA = __expf(dtv * Ads);
        h = dA * h + dtv * sxd[t * 40 + 6 + s] * sxi[t * 16 + dl];
        float p = h * sxd[t * 40 + 22 + s];
        p = dpp_add16_<0x128>(p);   // += row_ror:8
        p = dpp_add16_<0x124>(p);   // += row_ror:4
        p = dpp_add16_<0x122>(p);   // += row_ror:2
        p = dpp_add16_<0x121>(p);   // += row_ror:1  -> all 16 lanes hold sum
        if (s == 0) sy[t * 16 + dl] = p;
    }
    __syncthreads();
    for (int i = tid; i < 1024; i += 256) {
        int t = i >> 4, j = i & 15;
        float gate = siluf_(szs[i]);
        yg[(b * LQ + t0 + t) * DI + d0 + j] = (sy[i] + sxi[i] * Dp[d0 + j]) * gate;
    }
}

// ---------------- K7: out_proj GEMM, store transposed to NCHW xm[b,c,l] ----------------
// grid (L/64, 3, B)
__global__ __launch_bounds__(256) void k7_outproj(const float* __restrict__ yg,
    const float* __restrict__ wo, float* __restrict__ xm)
{
    const int l0 = blockIdx.x * 64;
    const int n0 = blockIdx.y * 32;
    const int b  = blockIdx.z;
    __shared__ float syT[96 * 68];    // [k(half)][l]
    __shared__ float wtT[192 * 36];   // [k][n]
    const int tid = threadIdx.x;
    for (int i = tid; i < 32 * 48; i += 256) {
        int n = i / 48, kq = i - n * 48;
        float4 v = *(const float4*)&wo[(n0 + n) * DI + kq * 4];
        wtT[(kq * 4 + 0) * 36 + n] = v.x;
        wtT[(kq * 4 + 1) * 36 + n] = v.y;
        wtT[(kq * 4 + 2) * 36 + n] = v.z;
        wtT[(kq * 4 + 3) * 36 + n] = v.w;
    }
    const int tx = tid & 15;   // l quad
    const int ty = tid >> 4;   // n pair
    float acc[2][4];
#pragma unroll
    for (int j = 0; j < 2; ++j)
#pragma unroll
        for (int i = 0; i < 4; ++i) acc[j][i] = 0.f;
    for (int half = 0; half < 2; ++half) {
        __syncthreads();
        for (int i = tid; i < 64 * 24; i += 256) {
            int l = i / 24, kq = i - l * 24;
            float4 v = *(const float4*)&yg[(b * LQ + l0 + l) * DI + half * 96 + kq * 4];
            syT[(kq * 4 + 0) * 68 + l] = v.x;
            syT[(kq * 4 + 1) * 68 + l] = v.y;
            syT[(kq * 4 + 2) * 68 + l] = v.z;
            syT[(kq * 4 + 3) * 68 + l] = v.w;
        }
        __syncthreads();
        for (int k = 0; k < 96; ++k) {
            float4 a = *(const float4*)&syT[k * 68 + tx * 4];
            int kk = half * 96 + k;
            float b0 = wtT[kk * 36 + ty * 2 + 0];
            float b1 = wtT[kk * 36 + ty * 2 + 1];
            acc[0][0] += a.x * b0; acc[0][1] += a.y * b0;
            acc[0][2] += a.z * b0; acc[0][3] += a.w * b0;
            acc[1][0] += a.x * b1; acc[1][1] += a.y * b1;
            acc[1][2] += a.z * b1; acc[1][3] += a.w * b1;
        }
    }
#pragma unroll
    for (int j = 0; j < 2; ++j) {
        float4 v = make_float4(acc[j][0], acc[j][1], acc[j][2], acc[j][3]);
        *(float4*)&xm[(b * 96 + n0 + ty * 2 + j) * LQ + l0 + tx * 4] = v;
    }
}

// ---------------- K8 v10: 3x3 conv partials, occupancy-forced (v9 + weight-staging fix) ----------------
// Block 256 = 64 spatial (16 col-quads x 4 rows, 4px each) x 4 wave-uniform co-quads.
// Thread: 4px x 4co (acc[4][4]). Block tile: 64 cols x 4 rows x 16 co, 24 ci (ks split x4).
// grid (6 co-tiles x 4 ks, 16 y, 4 b) = 1536 blocks.
// __launch_bounds__(256, 4): HARD VGPR cap 128 -> 4 waves/SIMD, 16 waves/CU.
// r9 BUG (fixed): weight staging loaded only 12 of the block's 16 co -> swt slots 12..15
// uninitialized -> co-quad 3 used garbage (absmax 3.2e-3). Now K8_WNEL = 4*9*16.
#define K8_ST 68
#define K8_INEL (4 * 6 * 66)    // 1584
#define K8_WNEL (4 * 9 * 16)    // 576
__global__ __launch_bounds__(256, 4) void k8_conv3(const float* __restrict__ xm,
    const float* __restrict__ w2, float* __restrict__ pbuf)
{
    const int ks  = blockIdx.x & 3;
    const int co0 = (blockIdx.x >> 2) * 16;
    const int y0  = blockIdx.y * 4;
    const int b   = blockIdx.z;
    __shared__ float sin_[4 * 6 * K8_ST];   // 1632 floats
    __shared__ float swt[4 * 9 * 16];       // 576 floats
    const int tid = threadIdx.x;
    const int sx = tid & 15;
    const int sy = (tid >> 4) & 3;
    const int cq = tid >> 6;                // wave-uniform co-quad (0..3)

    // --- staging slot precompute: input (7 slots @ 256 threads) ---
    int in_lds[7], in_goff[7];
    bool in_ok[7], in_act[7];
#pragma unroll
    for (int j = 0; j < 7; ++j) {
        int i = tid + j * 256;
        bool act = i < K8_INEL;
        int ci  = i / 396;
        int rem = i - ci * 396;
        int row = rem / 66;
        int col = rem - row * 66 - 1;       // -1..64
        int gy  = y0 + row - 1;
        bool ok = act && gy >= 0 && gy < 64 && col >= 0 && col < 64;
        in_act[j] = act;
        in_ok[j]  = ok;
        in_lds[j] = (ci * 6 + row) * K8_ST + col + 1;
        in_goff[j] = ok ? (ci * 4096 + gy * 64 + col) : 0;
    }
    // --- weight slots (3): 576 elems, [ci][k][co 0..15] ---
    int w_lds[3], w_goff[3];
    bool w_act[3];
#pragma unroll
    for (int j = 0; j < 3; ++j) {
        int i = tid + j * 256;
        bool act = i < K8_WNEL;
        int ci  = i / 144;
        int rem = i - ci * 144;
        int k   = rem >> 4;
        int cl  = rem & 15;
        w_act[j] = act;
        w_lds[j] = (ci * 9 + k) * 16 + cl;
        w_goff[j] = act ? (cl * 864 + ci * 9 + k) : 0;
    }

    const float* xb = xm + (size_t)b * 96 * 4096 + (size_t)ks * 24 * 4096;
    const float* wb = w2 + (size_t)co0 * 864 + ks * 24 * 9;

    // --- initial stage (chunk 0) ---
#pragma unroll
    for (int j = 0; j < 7; ++j)
        if (in_act[j]) sin_[in_lds[j]] = in_ok[j] ? xb[in_goff[j]] : 0.f;
#pragma unroll
    for (int j = 0; j < 3; ++j)
        if (w_act[j]) swt[w_lds[j]] = wb[w_goff[j]];
    __syncthreads();

    float acc[4][4];
#pragma unroll
    for (int c = 0; c < 4; ++c)
#pragma unroll
        for (int x = 0; x < 4; ++x) acc[c][x] = 0.f;

#pragma clang loop unroll(disable)
    for (int ch = 0; ch < 6; ++ch) {
        const bool havenext = ch < 5;
        float pin[7], pwt[3];
        if (havenext) {
            const float* xn = xb + (size_t)(ch + 1) * 4 * 4096;
            const float* wn = wb + (ch + 1) * 4 * 9;
#pragma unroll
            for (int j = 0; j < 7; ++j)
                pin[j] = in_ok[j] ? xn[in_goff[j]] : 0.f;
#pragma unroll
            for (int j = 0; j < 3; ++j)
                pwt[j] = w_act[j] ? wn[w_goff[j]] : 0.f;
        }

        // --- compute on current chunk ---
#pragma unroll
        for (int cii = 0; cii < 4; ++cii) {
            float w6[3][6];
#pragma unroll
            for (int r = 0; r < 3; ++r) {
                const float* rp = &sin_[(cii * 6 + sy + r) * K8_ST + sx * 4];
                float4 m = *(const float4*)rp;        // cols 4sx-1..4sx+2
                float2 e = *(const float2*)(rp + 4);  // cols 4sx+3..4sx+4
                w6[r][0] = m.x; w6[r][1] = m.y; w6[r][2] = m.z;
                w6[r][3] = m.w; w6[r][4] = e.x; w6[r][5] = e.y;
            }
#pragma unroll
            for (int ky = 0; ky < 3; ++ky) {
#pragma unroll
                for (int kx = 0; kx < 3; ++kx) {
                    const float* wp = &swt[(cii * 9 + ky * 3 + kx) * 16 + cq * 4];
                    float4 wv = *(const float4*)wp;   // wave-uniform b128 broadcast
#pragma unroll
                    for (int x = 0; x < 4; ++x) {
                        float pv = w6[ky][x + kx];
                        acc[0][x] = fmaf(pv, wv.x, acc[0][x]);
                        acc[1][x] = fmaf(pv, wv.y, acc[1][x]);
                        acc[2][x] = fmaf(pv, wv.z, acc[2][x]);
                        acc[3][x] = fmaf(pv, wv.w, acc[3][x]);
                    }
                }
            }
        }

        if (havenext) {
            __syncthreads();
#pragma unroll
            for (int j = 0; j < 7; ++j)
                if (in_act[j]) sin_[in_lds[j]] = pin[j];
#pragma unroll
            for (int j = 0; j < 3; ++j)
                if (w_act[j]) swt[w_lds[j]] = pwt[j];
            __syncthreads();
        }
    }

    // --- store fp32 partials: pbuf[ks][b][co][y][x] ---
    const int yy = y0 + sy;
    float* pb = pbuf + (size_t)ks * 1572864;
#pragma unroll
    for (int c = 0; c < 4; ++c) {
        const int cc = co0 + cq * 4 + c;
        float4 o = make_float4(acc[c][0], acc[c][1], acc[c][2], acc[c][3]);
        *(float4*)&pb[((size_t)(b * 96 + cc) * 64 + yy) * 64 + sx * 4] = o;
    }
}

// ---------------- K9: reduce 4 partials + BN + ReLU6 ----------------
// grid 1536, block 256; thread = 4 consecutive px (same channel).
__global__ __launch_bounds__(256) void k9_reduce(const float* __restrict__ pbuf,
    const float* __restrict__ bng, const float* __restrict__ bnb,
    const float* __restrict__ bnm, const float* __restrict__ bnv,
    float* __restrict__ out)
{
    const int q = blockIdx.x * 256 + threadIdx.x;   // quad index, 393216 total
    const int idx = q * 4;
    const int c = (idx >> 12) % 96;
    float4 s = *(const float4*)&pbuf[idx];
    float4 s1 = *(const float4*)&pbuf[idx + 1572864];
    float4 s2 = *(const float4*)&pbuf[idx + 2 * 1572864];
    float4 s3 = *(const float4*)&pbuf[idx + 3 * 1572864];
    s.x += s1.x + s2.x + s3.x;
    s.y += s1.y + s2.y + s3.y;
    s.z += s1.z + s2.z + s3.z;
    s.w += s1.w + s2.w + s3.w;
    float inv = bng[c] / sqrtf(bnv[c] + 1e-5f);
    float add = bnb[c] - bnm[c] * inv;
    float4 o;
    o.x = fminf(fmaxf(s.x * inv + add, 0.f), 6.f);
    o.y = fminf(fmaxf(s.y * inv + add, 0.f), 6.f);
    o.z = fminf(fmaxf(s.z * inv + add, 0.f), 6.f);
    o.w = fminf(fmaxf(s.w * inv + add, 0.f), 6.f);
    *(float4*)&out[idx] = o;
}

extern "C" void kernel_launch(void* const* d_in, const int* in_sizes, int n_in,
                              void* d_out, int out_size, void* d_ws, size_t ws_size,
                              hipStream_t stream) {
    (void)in_sizes; (void)n_in; (void)out_size; (void)ws_size;
    const float* x    = (const float*)d_in[0];
    const float* w_in = (const float*)d_in[1];
    const float* cw   = (const float*)d_in[2];
    const float* cb   = (const float*)d_in[3];
    const float* xw   = (const float*)d_in[4];
    const float* dtw  = (const float*)d_in[5];
    const float* dtb  = (const float*)d_in[6];
    const float* alog = (const float*)d_in[7];
    const float* Dp   = (const float*)d_in[8];
    const float* wo   = (const float*)d_in[9];
    const float* w2   = (const float*)d_in[10];
    const float* bng  = (const float*)d_in[11];
    const float* bnb  = (const float*)d_in[12];
    const float* bnm  = (const float*)d_in[13];
    const float* bnv  = (const float*)d_in[14];

    float* ws = (float*)d_ws;
    float* xi_raw = ws;                    // 3,145,728 (reused as yg after K2, pbuf after K7)
    float* z      = ws + 3145728;          // 3,145,728 (pbuf tail after K6)
    float* xi     = ws + 6291456;          // 3,145,728
    float* xdbl   = ws + 9437184;          //   622,592
    float* cA     = ws + 10059776;         //   786,432
    float* cB     = ws + 10846208;         //   786,432
    float* hinit  = ws + 11632640;         //   786,432
    float* xm     = ws + 12419072;         // 1,572,864   (total 13,991,936 floats = 56 MB)
    float* yg     = xi_raw;
    float* pbuf   = xi_raw;                // 4 x 1,572,864 = 6,291,456 floats (xi_raw + z)

    dim3 blk(256);
    k1_inproj<<<dim3(64, 6, 4), blk, 0, stream>>>(x, w_in, xi_raw, z);
    k2_conv1d<<<dim3(12288), blk, 0, stream>>>(xi_raw, cw, cb, xi);
    k3_xdbl<<<dim3(64, 4), blk, 0, stream>>>(xi, xw, xdbl);
    k4_scanA<<<dim3(NCHUNK, 12, 4), blk, 0, stream>>>(xdbl, xi, dtw, dtb, alog, cA, cB);
    k5_combine<<<dim3(48), blk, 0, stream>>>(cA, cB, hinit);
    k6_scanC<<<dim3(NCHUNK, 12, 4), blk, 0, stream>>>(xdbl, xi, z, dtw, dtb, alog, Dp, hinit, yg);
    k7_outproj<<<dim3(64, 3, 4), blk, 0, stream>>>(yg, wo, xm);
    k8_conv3<<<dim3(24, 16, 4), blk, 0, stream>>>(xm, w2, pbuf);
    k9_reduce<<<dim3(1536), blk, 0, stream>>>(pbuf, bng, bnb, bnm, bnv, (float*)d_out);
}

// Round 11
// 333.041 us; speedup vs baseline: 3.4349x; 3.4349x over previous
//
#include <hip/hip_runtime.h>
#include <math.h>

#define LQ 4096
#define DI 192
#define DS 16
#define NCHUNK 64

__device__ __forceinline__ float siluf_(float v) { return v / (1.f + __expf(-v)); }
__device__ __forceinline__ float softplusf_(float v) { return v > 20.f ? v : log1pf(__expf(v)); }

// 16-lane rotate-reduce step: x += row_ror<CTRL>(x). CTRL: 0x121+N-1 = row_ror:N.
template <int CTRL>
__device__ __forceinline__ float dpp_add16_(float x) {
    int y = __builtin_amdgcn_update_dpp(0, __float_as_int(x), CTRL, 0xf, 0xf, true);
    return x + __int_as_float(y);
}
// DPP lane shift within 16-lane rows; bound_ctrl -> 0 at row edges (= image zero-pad).
template <int CTRL>
__device__ __forceinline__ float dpp_shift_(float x) {
    int y = __builtin_amdgcn_update_dpp(0, __float_as_int(x), CTRL, 0xf, 0xf, true);
    return __int_as_float(y);
}

// ---------------- K1: in_proj GEMM  xz[b,l,n] = sum_c x[b,c,l] * W[n,c] ----------------
// grid (L/64, 6, B), block 256. n-tile<192 -> xi_raw, else z.
__global__ __launch_bounds__(256) void k1_inproj(const float* __restrict__ x,
    const float* __restrict__ w, float* __restrict__ xi_raw, float* __restrict__ z)
{
    const int l0 = blockIdx.x * 64;
    const int n0 = blockIdx.y * 64;
    const int b  = blockIdx.z;
    __shared__ float xs[96 * 64];    // [c][l]
    __shared__ float wsT[96 * 68];   // [c][n], padded stride 68
    const int tid = threadIdx.x;
    for (int i = tid; i < 96 * 16; i += 256) {
        int c = i >> 4, lq = i & 15;
        *(float4*)&xs[c * 64 + lq * 4] =
            *(const float4*)&x[(b * 96 + c) * LQ + l0 + lq * 4];
    }
    for (int i = tid; i < 64 * 24; i += 256) {
        int n = i / 24, cq = i - n * 24;
        float4 v = *(const float4*)&w[(n0 + n) * 96 + cq * 4];
        wsT[(cq * 4 + 0) * 68 + n] = v.x;
        wsT[(cq * 4 + 1) * 68 + n] = v.y;
        wsT[(cq * 4 + 2) * 68 + n] = v.z;
        wsT[(cq * 4 + 3) * 68 + n] = v.w;
    }
    __syncthreads();
    const int tx = tid & 15;   // n quad
    const int ty = tid >> 4;   // l quad
    float acc[4][4];
#pragma unroll
    for (int i = 0; i < 4; ++i)
#pragma unroll
        for (int j = 0; j < 4; ++j) acc[i][j] = 0.f;
    for (int k = 0; k < 96; ++k) {
        float4 a  = *(const float4*)&xs[k * 64 + ty * 4];
        float4 bb = *(const float4*)&wsT[k * 68 + tx * 4];
        float av[4] = {a.x, a.y, a.z, a.w};
        float bv[4] = {bb.x, bb.y, bb.z, bb.w};
#pragma unroll
        for (int i = 0; i < 4; ++i)
#pragma unroll
            for (int j = 0; j < 4; ++j) acc[i][j] += av[i] * bv[j];
    }
    float* dst = (n0 < DI) ? xi_raw : z;
    const int nn0 = (n0 < DI) ? n0 : (n0 - DI);
#pragma unroll
    for (int i = 0; i < 4; ++i) {
        int l = l0 + ty * 4 + i;
        float4 v = make_float4(acc[i][0], acc[i][1], acc[i][2], acc[i][3]);
        *(float4*)&dst[(b * LQ + l) * DI + nn0 + tx * 4] = v;
    }
}

// ---------------- K2: causal depthwise conv1d + bias + SiLU ----------------
__global__ __launch_bounds__(256) void k2_conv1d(const float* __restrict__ xir,
    const float* __restrict__ cw, const float* __restrict__ cb, float* __restrict__ xi)
{
    int idx = blockIdx.x * 256 + threadIdx.x;       // b*L*DI total
    int d = idx % DI;
    int l = (idx / DI) & (LQ - 1);
    float4 wv = *(const float4*)&cw[d * 4];
    float wk[4] = {wv.x, wv.y, wv.z, wv.w};
    float acc = cb[d];
#pragma unroll
    for (int k = 0; k < 4; ++k) {
        int lp = l - 3 + k;
        if (lp >= 0) acc += wk[k] * xir[idx + (k - 3) * DI];
    }
    xi[idx] = siluf_(acc);
}

// ---------------- K3: x_dbl[b,l,n] = sum_k xi[b,l,k] * xw[n,k], n<38 ----------------
// grid (L/64, B). K staged in two halves (LDS < 64KB).
__global__ __launch_bounds__(256) void k3_xdbl(const float* __restrict__ xi,
    const float* __restrict__ xw, float* __restrict__ xdbl)
{
    const int l0 = blockIdx.x * 64;
    const int b  = blockIdx.y;
    __shared__ float sxiT[96 * 68];   // [k(half)][l]
    __shared__ float swx[38 * 196];   // [n][k], padded
    const int tid = threadIdx.x;
    for (int i = tid; i < 38 * 48; i += 256) {
        int n = i / 48, kq = i - n * 48;
        *(float4*)&swx[n * 196 + kq * 4] = *(const float4*)&xw[n * 192 + kq * 4];
    }
    const int lq = tid & 15, ng = tid >> 4;
    float acc[3][4];
#pragma unroll
    for (int p = 0; p < 3; ++p)
#pragma unroll
        for (int i = 0; i < 4; ++i) acc[p][i] = 0.f;
    for (int half = 0; half < 2; ++half) {
        __syncthreads();
        for (int i = tid; i < 64 * 24; i += 256) {
            int l = i / 24, kq = i - l * 24;
            float4 v = *(const float4*)&xi[(b * LQ + l0 + l) * DI + half * 96 + kq * 4];
            sxiT[(kq * 4 + 0) * 68 + l] = v.x;
            sxiT[(kq * 4 + 1) * 68 + l] = v.y;
            sxiT[(kq * 4 + 2) * 68 + l] = v.z;
            sxiT[(kq * 4 + 3) * 68 + l] = v.w;
        }
        __syncthreads();
#pragma unroll
        for (int pass = 0; pass < 3; ++pass) {
            int n = pass * 16 + ng;
            if (n >= 38) continue;
            for (int k = 0; k < 96; ++k) {
                float4 a = *(const float4*)&sxiT[k * 68 + lq * 4];
                float bv = swx[n * 196 + half * 96 + k];
                acc[pass][0] += a.x * bv;
                acc[pass][1] += a.y * bv;
                acc[pass][2] += a.z * bv;
                acc[pass][3] += a.w * bv;
            }
        }
    }
#pragma unroll
    for (int pass = 0; pass < 3; ++pass) {
        int n = pass * 16 + ng;
        if (n >= 38) continue;
#pragma unroll
        for (int i = 0; i < 4; ++i)
            xdbl[(b * LQ + l0 + lq * 4 + i) * 38 + n] = acc[pass][i];
    }
}

// ---------------- K4: scan pass A — per-chunk (prod dA, affine tail), h0 = 0 ----------------
// grid (NCHUNK, 12, B), block 256 = 16 d x 16 s
__global__ __launch_bounds__(256) void k4_scanA(
    const float* __restrict__ xdbl, const float* __restrict__ xi,
    const float* __restrict__ dtw, const float* __restrict__ dtb,
    const float* __restrict__ alog,
    float* __restrict__ cA, float* __restrict__ cB)
{
    const int ch = blockIdx.x, g = blockIdx.y, b = blockIdx.z;
    const int t0 = ch * 64, d0 = g * 16;
    __shared__ float sxd[64 * 40];
    __shared__ float sdt[1024], sxi[1024];
    __shared__ float sdtw[96], sdtb[16];
    const int tid = threadIdx.x;
    for (int i = tid; i < 64 * 38; i += 256) {
        int t = i / 38, cc = i - t * 38;
        sxd[t * 40 + cc] = xdbl[(b * LQ + t0 + t) * 38 + cc];
    }
    for (int i = tid; i < 1024; i += 256) {
        int t = i >> 4, j = i & 15;
        sxi[i] = xi[(b * LQ + t0 + t) * DI + d0 + j];
    }
    if (tid < 96) sdtw[tid] = dtw[d0 * 6 + tid];
    if (tid < 16) sdtb[tid] = dtb[d0 + tid];
    __syncthreads();
    for (int i = tid; i < 1024; i += 256) {
        int t = i >> 4, dl = i & 15;
        float acc = sdtb[dl];
#pragma unroll
        for (int r = 0; r < 6; ++r) acc += sxd[t * 40 + r] * sdtw[dl * 6 + r];
        sdt[i] = softplusf_(acc);
    }
    __syncthreads();
    const int s = tid & 15, dl = tid >> 4;
    const float Ads = -__expf(alog[(d0 + dl) * DS + s]);
    float a = 1.f, hb = 0.f;
#pragma unroll 4
    for (int t = 0; t < 64; ++t) {
        float dtv = sdt[t * 16 + dl];
        float dA = __expf(dtv * Ads);
        float dbx = dtv * sxd[t * 40 + 6 + s] * sxi[t * 16 + dl];
        a *= dA;
        hb = dA * hb + dbx;
    }
    int o = ((b * NCHUNK + ch) * DI + d0 + dl) * DS + s;
    cA[o] = a;
    cB[o] = hb;
}

// ---------------- K5: sequential combine over chunks -> h_init per chunk ----------------
__global__ __launch_bounds__(256) void k5_combine(const float* __restrict__ cA,
    const float* __restrict__ cB, float* __restrict__ hinit)
{
    int gid = blockIdx.x * 256 + threadIdx.x;   // 4*192*16 = 12288
    int b = gid / 3072;
    int rem = gid - b * 3072;
    int base = b * (NCHUNK * 3072) + rem;
    float h = 0.f;
#pragma unroll 8
    for (int c = 0; c < NCHUNK; ++c) {
        int o = base + c * 3072;
        hinit[o] = h;
        h = cA[o] * h + cB[o];
    }
}

// ---------------- K6: scan pass C — replay with true h_init, y = C.h, gate ----------------
// s-group reduction via DPP row_ror rotate-reduce (VALU), not shfl/LDS.
__global__ __launch_bounds__(256) void k6_scanC(
    const float* __restrict__ xdbl, const float* __restrict__ xi,
    const float* __restrict__ z, const float* __restrict__ dtw,
    const float* __restrict__ dtb, const float* __restrict__ alog,
    const float* __restrict__ Dp, const float* __restrict__ hinit,
    float* __restrict__ yg)
{
    const int ch = blockIdx.x, g = blockIdx.y, b = blockIdx.z;
    const int t0 = ch * 64, d0 = g * 16;
    __shared__ float sxd[64 * 40];
    __shared__ float sdt[1024], sxi[1024], szs[1024], sy[1024];
    __shared__ float sdtw[96], sdtb[16];
    const int tid = threadIdx.x;
    for (int i = tid; i < 64 * 38; i += 256) {
        int t = i / 38, cc = i - t * 38;
        sxd[t * 40 + cc] = xdbl[(b * LQ + t0 + t) * 38 + cc];
    }
    for (int i = tid; i < 1024; i += 256) {
        int t = i >> 4, j = i & 15;
        int row = b * LQ + t0 + t;
        sxi[i] = xi[row * DI + d0 + j];
        szs[i] = z[row * DI + d0 + j];
    }
    if (tid < 96) sdtw[tid] = dtw[d0 * 6 + tid];
    if (tid < 16) sdtb[tid] = dtb[d0 + tid];
    __syncthreads();
    for (int i = tid; i < 1024; i += 256) {
        int t = i >> 4, dl = i & 15;
        float acc = sdtb[dl];
#pragma unroll
        for (int r = 0; r < 6; ++r) acc += sxd[t * 40 + r] * sdtw[dl * 6 + r];
        sdt[i] = softplusf_(acc);
    }
    __syncthreads();
    const int s = tid & 15, dl = tid >> 4;
    const float Ads = -__expf(alog[(d0 + dl) * DS + s]);
    float h = hinit[((b * NCHUNK + ch) * DI + d0 + dl) * DS + s];
    for (int t = 0; t < 64; ++t) {
        float dtv = sdt[t * 16 + dl];
        float dA = __expf(dtv * Ads);
        h = dA * h + dtv * sxd[t * 40 + 6 + s] * sxi[t * 16 + dl];
        float p = h * sxd[t * 40 + 22 + s];
        p = dpp_add16_<0x128>(p);   // += row_ror:8
        p = dpp_add16_<0x124>(p);   // += row_ror:4
        p = dpp_add16_<0x122>(p);   // += row_ror:2
        p = dpp_add16_<0x121>(p);   // += row_ror:1  -> all 16 lanes hold sum
        if (s == 0) sy[t * 16 + dl] = p;
    }
    __syncthreads();
    for (int i = tid; i < 1024; i += 256) {
        int t = i >> 4, j = i & 15;
        float gate = siluf_(szs[i]);
        yg[(b * LQ + t0 + t) * DI + d0 + j] = (sy[i] + sxi[i] * Dp[d0 + j]) * gate;
    }
}

// ---------------- K7: out_proj GEMM, store transposed to NCHW xm[b,c,l] ----------------
// grid (L/64, 3, B)
__global__ __launch_bounds__(256) void k7_outproj(const float* __restrict__ yg,
    const float* __restrict__ wo, float* __restrict__ xm)
{
    const int l0 = blockIdx.x * 64;
    const int n0 = blockIdx.y * 32;
    const int b  = blockIdx.z;
    __shared__ float syT[96 * 68];    // [k(half)][l]
    __shared__ float wtT[192 * 36];   // [k][n]
    const int tid = threadIdx.x;
    for (int i = tid; i < 32 * 48; i += 256) {
        int n = i / 48, kq = i - n * 48;
        float4 v = *(const float4*)&wo[(n0 + n) * DI + kq * 4];
        wtT[(kq * 4 + 0) * 36 + n] = v.x;
        wtT[(kq * 4 + 1) * 36 + n] = v.y;
        wtT[(kq * 4 + 2) * 36 + n] = v.z;
        wtT[(kq * 4 + 3) * 36 + n] = v.w;
    }
    const int tx = tid & 15;   // l quad
    const int ty = tid >> 4;   // n pair
    float acc[2][4];
#pragma unroll
    for (int j = 0; j < 2; ++j)
#pragma unroll
        for (int i = 0; i < 4; ++i) acc[j][i] = 0.f;
    for (int half = 0; half < 2; ++half) {
        __syncthreads();
        for (int i = tid; i < 64 * 24; i += 256) {
            int l = i / 24, kq = i - l * 24;
            float4 v = *(const float4*)&yg[(b * LQ + l0 + l) * DI + half * 96 + kq * 4];
            syT[(kq * 4 + 0) * 68 + l] = v.x;
            syT[(kq * 4 + 1) * 68 + l] = v.y;
            syT[(kq * 4 + 2) * 68 + l] = v.z;
            syT[(kq * 4 + 3) * 68 + l] = v.w;
        }
        __syncthreads();
        for (int k = 0; k < 96; ++k) {
            float4 a = *(const float4*)&syT[k * 68 + tx * 4];
            int kk = half * 96 + k;
            float b0 = wtT[kk * 36 + ty * 2 + 0];
            float b1 = wtT[kk * 36 + ty * 2 + 1];
            acc[0][0] += a.x * b0; acc[0][1] += a.y * b0;
            acc[0][2] += a.z * b0; acc[0][3] += a.w * b0;
            acc[1][0] += a.x * b1; acc[1][1] += a.y * b1;
            acc[1][2] += a.z * b1; acc[1][3] += a.w * b1;
        }
    }
#pragma unroll
    for (int j = 0; j < 2; ++j) {
        float4 v = make_float4(acc[j][0], acc[j][1], acc[j][2], acc[j][3]);
        *(float4*)&xm[(b * 96 + n0 + ty * 2 + j) * LQ + l0 + tx * 4] = v;
    }
}

// ---------------- K8 v11: 3x3 conv partials — halo-free LDS + DPP lane-shift halo ----------------
// Block 256 = 64 spatial (16 col-quads x 4 rows, 4px) x 4 wave-uniform co-quads.
// grid (6 co x 4 ks, 16 y, 4 b) = 1536 blocks (6/CU). Each block: 16 co, 24 ci (6 chunks).
// Input LDS [ci][row][64] contiguous, NO halo: the window's col 4sx-1 comes from lane sx-1
// via DPP row_shr:1 (bound_ctrl=0 -> 0 at sx=0 = image zero-pad), col 4sx+4 via row_shl:1.
// The 16-lane DPP row == one image row (tid = sx + 16*sy + 64*cq). Staging is float4
// (2 slots/thread) -> tiny register state; no launch_bounds force (r10: forcing -> 3.4 GB spill).
#define K8_INQ (4 * 6 * 16)     // 384 staged float4 quads
#define K8_WNEL (4 * 9 * 16)    // 576 staged weight floats
__global__ __launch_bounds__(256) void k8_conv3(const float* __restrict__ xm,
    const float* __restrict__ w2, float* __restrict__ pbuf)
{
    const int ks  = blockIdx.x & 3;
    const int co0 = (blockIdx.x >> 2) * 16;
    const int y0  = blockIdx.y * 4;
    const int b   = blockIdx.z;
    __shared__ float sin_[4 * 6 * 64];      // 1536 floats, stride 64
    __shared__ float swt[4 * 9 * 16];       // 576 floats
    const int tid = threadIdx.x;
    const int sx = tid & 15;
    const int sy = (tid >> 4) & 3;
    const int cq = tid >> 6;                // wave-uniform co-quad (0..3)

    // --- input staging: 384 float4 slots, 2 per thread ---
    int in_lds[2], in_goff[2];
    bool in_ok[2], in_act[2];
#pragma unroll
    for (int j = 0; j < 2; ++j) {
        int i = tid + j * 256;
        bool act = i < K8_INQ;
        int ci  = i / 96;
        int rem = i - ci * 96;
        int row = rem >> 4;
        int qx  = rem & 15;
        int gy  = y0 + row - 1;
        bool ok = act && gy >= 0 && gy < 64;
        in_act[j] = act;
        in_ok[j]  = ok;
        in_lds[j] = (ci * 6 + row) * 64 + qx * 4;
        in_goff[j] = ok ? (ci * 4096 + gy * 64 + qx * 4) : 0;
    }
    // --- weight slots (3): 576 elems, [ci][k][co 0..15] ---
    int w_lds[3], w_goff[3];
    bool w_act[3];
#pragma unroll
    for (int j = 0; j < 3; ++j) {
        int i = tid + j * 256;
        bool act = i < K8_WNEL;
        int ci  = i / 144;
        int rem = i - ci * 144;
        int k   = rem >> 4;
        int cl  = rem & 15;
        w_act[j] = act;
        w_lds[j] = (ci * 9 + k) * 16 + cl;
        w_goff[j] = act ? (cl * 864 + ci * 9 + k) : 0;
    }

    const float* xb = xm + (size_t)b * 96 * 4096 + (size_t)ks * 24 * 4096;
    const float* wb = w2 + (size_t)co0 * 864 + ks * 24 * 9;
    const float4 zero4 = make_float4(0.f, 0.f, 0.f, 0.f);

    // --- initial stage (chunk 0) ---
#pragma unroll
    for (int j = 0; j < 2; ++j)
        if (in_act[j]) *(float4*)&sin_[in_lds[j]] =
            in_ok[j] ? *(const float4*)&xb[in_goff[j]] : zero4;
#pragma unroll
    for (int j = 0; j < 3; ++j)
        if (w_act[j]) swt[w_lds[j]] = wb[w_goff[j]];
    __syncthreads();

    float acc[4][4];
#pragma unroll
    for (int c = 0; c < 4; ++c)
#pragma unroll
        for (int x = 0; x < 4; ++x) acc[c][x] = 0.f;

#pragma clang loop unroll(disable)
    for (int ch = 0; ch < 6; ++ch) {
        const bool havenext = ch < 5;
        float4 pin[2];
        float pwt[3];
        if (havenext) {
            const float* xn = xb + (size_t)(ch + 1) * 4 * 4096;
            const float* wn = wb + (ch + 1) * 4 * 9;
#pragma unroll
            for (int j = 0; j < 2; ++j)
                pin[j] = in_ok[j] ? *(const float4*)&xn[in_goff[j]] : zero4;
#pragma unroll
            for (int j = 0; j < 3; ++j)
                pwt[j] = w_act[j] ? wn[w_goff[j]] : 0.f;
        }

        // --- compute on current chunk ---
#pragma unroll
        for (int cii = 0; cii < 4; ++cii) {
            float w6[3][6];
#pragma unroll
            for (int r = 0; r < 3; ++r) {
                float4 v = *(const float4*)&sin_[(cii * 6 + sy + r) * 64 + sx * 4];
                w6[r][0] = dpp_shift_<0x111>(v.w);   // row_shr:1 -> col 4sx-1 (0 at sx=0)
                w6[r][1] = v.x; w6[r][2] = v.y; w6[r][3] = v.z; w6[r][4] = v.w;
                w6[r][5] = dpp_shift_<0x101>(v.x);   // row_shl:1 -> col 4sx+4 (0 at sx=15)
            }
#pragma unroll
            for (int ky = 0; ky < 3; ++ky) {
#pragma unroll
                for (int kx = 0; kx < 3; ++kx) {
                    const float* wp = &swt[(cii * 9 + ky * 3 + kx) * 16 + cq * 4];
                    float4 wv = *(const float4*)wp;   // wave-uniform b128 broadcast
#pragma unroll
                    for (int x = 0; x < 4; ++x) {
                        float pv = w6[ky][x + kx];
                        acc[0][x] = fmaf(pv, wv.x, acc[0][x]);
                        acc[1][x] = fmaf(pv, wv.y, acc[1][x]);
                        acc[2][x] = fmaf(pv, wv.z, acc[2][x]);
                        acc[3][x] = fmaf(pv, wv.w, acc[3][x]);
                    }
                }
            }
        }

        if (havenext) {
            __syncthreads();
#pragma unroll
            for (int j = 0; j < 2; ++j)
                if (in_act[j]) *(float4*)&sin_[in_lds[j]] = pin[j];
#pragma unroll
            for (int j = 0; j < 3; ++j)
                if (w_act[j]) swt[w_lds[j]] = pwt[j];
            __syncthreads();
        }
    }

    // --- store fp32 partials: pbuf[ks][b][co][y][x] ---
    const int yy = y0 + sy;
    float* pb = pbuf + (size_t)ks * 1572864;
#pragma unroll
    for (int c = 0; c < 4; ++c) {
        const int cc = co0 + cq * 4 + c;
        float4 o = make_float4(acc[c][0], acc[c][1], acc[c][2], acc[c][3]);
        *(float4*)&pb[((size_t)(b * 96 + cc) * 64 + yy) * 64 + sx * 4] = o;
    }
}

// ---------------- K9: reduce 4 partials + BN + ReLU6 ----------------
// grid 1536, block 256; thread = 4 consecutive px (same channel).
__global__ __launch_bounds__(256) void k9_reduce(const float* __restrict__ pbuf,
    const float* __restrict__ bng, const float* __restrict__ bnb,
    const float* __restrict__ bnm, const float* __restrict__ bnv,
    float* __restrict__ out)
{
    const int q = blockIdx.x * 256 + threadIdx.x;   // quad index, 393216 total
    const int idx = q * 4;
    const int c = (idx >> 12) % 96;
    float4 s = *(const float4*)&pbuf[idx];
    float4 s1 = *(const float4*)&pbuf[idx + 1572864];
    float4 s2 = *(const float4*)&pbuf[idx + 2 * 1572864];
    float4 s3 = *(const float4*)&pbuf[idx + 3 * 1572864];
    s.x += s1.x + s2.x + s3.x;
    s.y += s1.y + s2.y + s3.y;
    s.z += s1.z + s2.z + s3.z;
    s.w += s1.w + s2.w + s3.w;
    float inv = bng[c] / sqrtf(bnv[c] + 1e-5f);
    float add = bnb[c] - bnm[c] * inv;
    float4 o;
    o.x = fminf(fmaxf(s.x * inv + add, 0.f), 6.f);
    o.y = fminf(fmaxf(s.y * inv + add, 0.f), 6.f);
    o.z = fminf(fmaxf(s.z * inv + add, 0.f), 6.f);
    o.w = fminf(fmaxf(s.w * inv + add, 0.f), 6.f);
    *(float4*)&out[idx] = o;
}

extern "C" void kernel_launch(void* const* d_in, const int* in_sizes, int n_in,
                              void* d_out, int out_size, void* d_ws, size_t ws_size,
                              hipStream_t stream) {
    (void)in_sizes; (void)n_in; (void)out_size; (void)ws_size;
    const float* x    = (const float*)d_in[0];
    const float* w_in = (const float*)d_in[1];
    const float* cw   = (const float*)d_in[2];
    const float* cb   = (const float*)d_in[3];
    const float* xw   = (const float*)d_in[4];
    const float* dtw  = (const float*)d_in[5];
    const float* dtb  = (const float*)d_in[6];
    const float* alog = (const float*)d_in[7];
    const float* Dp   = (const float*)d_in[8];
    const float* wo   = (const float*)d_in[9];
    const float* w2   = (const float*)d_in[10];
    const float* bng  = (const float*)d_in[11];
    const float* bnb  = (const float*)d_in[12];
    const float* bnm  = (const float*)d_in[13];
    const float* bnv  = (const float*)d_in[14];

    float* ws = (float*)d_ws;
    float* xi_raw = ws;                    // 3,145,728 (reused as yg after K2, pbuf after K7)
    float* z      = ws + 3145728;          // 3,145,728 (pbuf tail after K6)
    float* xi     = ws + 6291456;          // 3,145,728
    float* xdbl   = ws + 9437184;          //   622,592
    float* cA     = ws + 10059776;         //   786,432
    float* cB     = ws + 10846208;         //   786,432
    float* hinit  = ws + 11632640;         //   786,432
    float* xm     = ws + 12419072;         // 1,572,864   (total 13,991,936 floats = 56 MB)
    float* yg     = xi_raw;
    float* pbuf   = xi_raw;                // 4 x 1,572,864 = 6,291,456 floats (xi_raw + z)

    dim3 blk(256);
    k1_inproj<<<dim3(64, 6, 4), blk, 0, stream>>>(x, w_in, xi_raw, z);
    k2_conv1d<<<dim3(12288), blk, 0, stream>>>(xi_raw, cw, cb, xi);
    k3_xdbl<<<dim3(64, 4), blk, 0, stream>>>(xi, xw, xdbl);
    k4_scanA<<<dim3(NCHUNK, 12, 4), blk, 0, stream>>>(xdbl, xi, dtw, dtb, alog, cA, cB);
    k5_combine<<<dim3(48), blk, 0, stream>>>(cA, cB, hinit);
    k6_scanC<<<dim3(NCHUNK, 12, 4), blk, 0, stream>>>(xdbl, xi, z, dtw, dtb, alog, Dp, hinit, yg);
    k7_outproj<<<dim3(64, 3, 4), blk, 0, stream>>>(yg, wo, xm);
    k8_conv3<<<dim3(24, 16, 4), blk, 0, stream>>>(xm, w2, pbuf);
    k9_reduce<<<dim3(1536), blk, 0, stream>>>(pbuf, bng, bnb, bnm, bnv, (float*)d_out);
}

// Round 12
// 281.474 us; speedup vs baseline: 4.0642x; 1.1832x over previous
//
#include <hip/hip_runtime.h>
#include <math.h>

#define LQ 4096
#define DI 192
#define DS 16
#define NCHUNK 64

__device__ __forceinline__ float siluf_(float v) { return v / (1.f + __expf(-v)); }
__device__ __forceinline__ float softplusf_(float v) { return v > 20.f ? v : log1pf(__expf(v)); }

// 16-lane rotate-reduce step: x += row_ror<CTRL>(x). CTRL: 0x121+N-1 = row_ror:N.
template <int CTRL>
__device__ __forceinline__ float dpp_add16_(float x) {
    int y = __builtin_amdgcn_update_dpp(0, __float_as_int(x), CTRL, 0xf, 0xf, true);
    return x + __int_as_float(y);
}
// DPP lane shift within 16-lane rows; bound_ctrl -> 0 at row edges (= image zero-pad).
template <int CTRL>
__device__ __forceinline__ float dpp_shift_(float x) {
    int y = __builtin_amdgcn_update_dpp(0, __float_as_int(x), CTRL, 0xf, 0xf, true);
    return __int_as_float(y);
}
// Async global->LDS. LDS dest = wave-uniform base + lane*size (pass identical l for all lanes).
__device__ __forceinline__ void async_g2l16_(const float* g, float* l) {
    __builtin_amdgcn_global_load_lds(
        (const __attribute__((address_space(1))) void*)g,
        (__attribute__((address_space(3))) void*)l, 16, 0, 0);
}
__device__ __forceinline__ void async_g2l4_(const float* g, float* l) {
    __builtin_amdgcn_global_load_lds(
        (const __attribute__((address_space(1))) void*)g,
        (__attribute__((address_space(3))) void*)l, 4, 0, 0);
}

// ---------------- K1: in_proj GEMM  xz[b,l,n] = sum_c x[b,c,l] * W[n,c] ----------------
// grid (L/64, 6, B), block 256. n-tile<192 -> xi_raw, else z.
__global__ __launch_bounds__(256) void k1_inproj(const float* __restrict__ x,
    const float* __restrict__ w, float* __restrict__ xi_raw, float* __restrict__ z)
{
    const int l0 = blockIdx.x * 64;
    const int n0 = blockIdx.y * 64;
    const int b  = blockIdx.z;
    __shared__ float xs[96 * 64];    // [c][l]
    __shared__ float wsT[96 * 68];   // [c][n], padded stride 68
    const int tid = threadIdx.x;
    for (int i = tid; i < 96 * 16; i += 256) {
        int c = i >> 4, lq = i & 15;
        *(float4*)&xs[c * 64 + lq * 4] =
            *(const float4*)&x[(b * 96 + c) * LQ + l0 + lq * 4];
    }
    for (int i = tid; i < 64 * 24; i += 256) {
        int n = i / 24, cq = i - n * 24;
        float4 v = *(const float4*)&w[(n0 + n) * 96 + cq * 4];
        wsT[(cq * 4 + 0) * 68 + n] = v.x;
        wsT[(cq * 4 + 1) * 68 + n] = v.y;
        wsT[(cq * 4 + 2) * 68 + n] = v.z;
        wsT[(cq * 4 + 3) * 68 + n] = v.w;
    }
    __syncthreads();
    const int tx = tid & 15;   // n quad
    const int ty = tid >> 4;   // l quad
    float acc[4][4];
#pragma unroll
    for (int i = 0; i < 4; ++i)
#pragma unroll
        for (int j = 0; j < 4; ++j) acc[i][j] = 0.f;
    for (int k = 0; k < 96; ++k) {
        float4 a  = *(const float4*)&xs[k * 64 + ty * 4];
        float4 bb = *(const float4*)&wsT[k * 68 + tx * 4];
        float av[4] = {a.x, a.y, a.z, a.w};
        float bv[4] = {bb.x, bb.y, bb.z, bb.w};
#pragma unroll
        for (int i = 0; i < 4; ++i)
#pragma unroll
            for (int j = 0; j < 4; ++j) acc[i][j] += av[i] * bv[j];
    }
    float* dst = (n0 < DI) ? xi_raw : z;
    const int nn0 = (n0 < DI) ? n0 : (n0 - DI);
#pragma unroll
    for (int i = 0; i < 4; ++i) {
        int l = l0 + ty * 4 + i;
        float4 v = make_float4(acc[i][0], acc[i][1], acc[i][2], acc[i][3]);
        *(float4*)&dst[(b * LQ + l) * DI + nn0 + tx * 4] = v;
    }
}

// ---------------- K2: causal depthwise conv1d + bias + SiLU ----------------
__global__ __launch_bounds__(256) void k2_conv1d(const float* __restrict__ xir,
    const float* __restrict__ cw, const float* __restrict__ cb, float* __restrict__ xi)
{
    int idx = blockIdx.x * 256 + threadIdx.x;       // b*L*DI total
    int d = idx % DI;
    int l = (idx / DI) & (LQ - 1);
    float4 wv = *(const float4*)&cw[d * 4];
    float wk[4] = {wv.x, wv.y, wv.z, wv.w};
    float acc = cb[d];
#pragma unroll
    for (int k = 0; k < 4; ++k) {
        int lp = l - 3 + k;
        if (lp >= 0) acc += wk[k] * xir[idx + (k - 3) * DI];
    }
    xi[idx] = siluf_(acc);
}

// ---------------- K3: x_dbl[b,l,n] = sum_k xi[b,l,k] * xw[n,k], n<38 ----------------
// grid (L/64, B). K staged in two halves (LDS < 64KB).
__global__ __launch_bounds__(256) void k3_xdbl(const float* __restrict__ xi,
    const float* __restrict__ xw, float* __restrict__ xdbl)
{
    const int l0 = blockIdx.x * 64;
    const int b  = blockIdx.y;
    __shared__ float sxiT[96 * 68];   // [k(half)][l]
    __shared__ float swx[38 * 196];   // [n][k], padded
    const int tid = threadIdx.x;
    for (int i = tid; i < 38 * 48; i += 256) {
        int n = i / 48, kq = i - n * 48;
        *(float4*)&swx[n * 196 + kq * 4] = *(const float4*)&xw[n * 192 + kq * 4];
    }
    const int lq = tid & 15, ng = tid >> 4;
    float acc[3][4];
#pragma unroll
    for (int p = 0; p < 3; ++p)
#pragma unroll
        for (int i = 0; i < 4; ++i) acc[p][i] = 0.f;
    for (int half = 0; half < 2; ++half) {
        __syncthreads();
        for (int i = tid; i < 64 * 24; i += 256) {
            int l = i / 24, kq = i - l * 24;
            float4 v = *(const float4*)&xi[(b * LQ + l0 + l) * DI + half * 96 + kq * 4];
            sxiT[(kq * 4 + 0) * 68 + l] = v.x;
            sxiT[(kq * 4 + 1) * 68 + l] = v.y;
            sxiT[(kq * 4 + 2) * 68 + l] = v.z;
            sxiT[(kq * 4 + 3) * 68 + l] = v.w;
        }
        __syncthreads();
#pragma unroll
        for (int pass = 0; pass < 3; ++pass) {
            int n = pass * 16 + ng;
            if (n >= 38) continue;
            for (int k = 0; k < 96; ++k) {
                float4 a = *(const float4*)&sxiT[k * 68 + lq * 4];
                float bv = swx[n * 196 + half * 96 + k];
                acc[pass][0] += a.x * bv;
                acc[pass][1] += a.y * bv;
                acc[pass][2] += a.z * bv;
                acc[pass][3] += a.w * bv;
            }
        }
    }
#pragma unroll
    for (int pass = 0; pass < 3; ++pass) {
        int n = pass * 16 + ng;
        if (n >= 38) continue;
#pragma unroll
        for (int i = 0; i < 4; ++i)
            xdbl[(b * LQ + l0 + lq * 4 + i) * 38 + n] = acc[pass][i];
    }
}

// ---------------- K4: scan pass A — per-chunk (prod dA, affine tail), h0 = 0 ----------------
// grid (NCHUNK, 12, B), block 256 = 16 d x 16 s
__global__ __launch_bounds__(256) void k4_scanA(
    const float* __restrict__ xdbl, const float* __restrict__ xi,
    const float* __restrict__ dtw, const float* __restrict__ dtb,
    const float* __restrict__ alog,
    float* __restrict__ cA, float* __restrict__ cB)
{
    const int ch = blockIdx.x, g = blockIdx.y, b = blockIdx.z;
    const int t0 = ch * 64, d0 = g * 16;
    __shared__ float sxd[64 * 40];
    __shared__ float sdt[1024], sxi[1024];
    __shared__ float sdtw[96], sdtb[16];
    const int tid = threadIdx.x;
    for (int i = tid; i < 64 * 38; i += 256) {
        int t = i / 38, cc = i - t * 38;
        sxd[t * 40 + cc] = xdbl[(b * LQ + t0 + t) * 38 + cc];
    }
    for (int i = tid; i < 1024; i += 256) {
        int t = i >> 4, j = i & 15;
        sxi[i] = xi[(b * LQ + t0 + t) * DI + d0 + j];
    }
    if (tid < 96) sdtw[tid] = dtw[d0 * 6 + tid];
    if (tid < 16) sdtb[tid] = dtb[d0 + tid];
    __syncthreads();
    for (int i = tid; i < 1024; i += 256) {
        int t = i >> 4, dl = i & 15;
        float acc = sdtb[dl];
#pragma unroll
        for (int r = 0; r < 6; ++r) acc += sxd[t * 40 + r] * sdtw[dl * 6 + r];
        sdt[i] = softplusf_(acc);
    }
    __syncthreads();
    const int s = tid & 15, dl = tid >> 4;
    const float Ads = -__expf(alog[(d0 + dl) * DS + s]);
    float a = 1.f, hb = 0.f;
#pragma unroll 4
    for (int t = 0; t < 64; ++t) {
        float dtv = sdt[t * 16 + dl];
        float dA = __expf(dtv * Ads);
        float dbx = dtv * sxd[t * 40 + 6 + s] * sxi[t * 16 + dl];
        a *= dA;
        hb = dA * hb + dbx;
    }
    int o = ((b * NCHUNK + ch) * DI + d0 + dl) * DS + s;
    cA[o] = a;
    cB[o] = hb;
}

// ---------------- K5: sequential combine over chunks -> h_init per chunk ----------------
__global__ __launch_bounds__(256) void k5_combine(const float* __restrict__ cA,
    const float* __restrict__ cB, float* __restrict__ hinit)
{
    int gid = blockIdx.x * 256 + threadIdx.x;   // 4*192*16 = 12288
    int b = gid / 3072;
    int rem = gid - b * 3072;
    int base = b * (NCHUNK * 3072) + rem;
    float h = 0.f;
#pragma unroll 8
    for (int c = 0; c < NCHUNK; ++c) {
        int o = base + c * 3072;
        hinit[o] = h;
        h = cA[o] * h + cB[o];
    }
}

// ---------------- K6: scan pass C — replay with true h_init, y = C.h, gate ----------------
// s-group reduction via DPP row_ror rotate-reduce (VALU), not shfl/LDS.
__global__ __launch_bounds__(256) void k6_scanC(
    const float* __restrict__ xdbl, const float* __restrict__ xi,
    const float* __restrict__ z, const float* __restrict__ dtw,
    const float* __restrict__ dtb, const float* __restrict__ alog,
    const float* __restrict__ Dp, const float* __restrict__ hinit,
    float* __restrict__ yg)
{
    const int ch = blockIdx.x, g = blockIdx.y, b = blockIdx.z;
    const int t0 = ch * 64, d0 = g * 16;
    __shared__ float sxd[64 * 40];
    __shared__ float sdt[1024], sxi[1024], szs[1024], sy[1024];
    __shared__ float sdtw[96], sdtb[16];
    const int tid = threadIdx.x;
    for (int i = tid; i < 64 * 38; i += 256) {
        int t = i / 38, cc = i - t * 38;
        sxd[t * 40 + cc] = xdbl[(b * LQ + t0 + t) * 38 + cc];
    }
    for (int i = tid; i < 1024; i += 256) {
        int t = i >> 4, j = i & 15;
        int row = b * LQ + t0 + t;
        sxi[i] = xi[row * DI + d0 + j];
        szs[i] = z[row * DI + d0 + j];
    }
    if (tid < 96) sdtw[tid] = dtw[d0 * 6 + tid];
    if (tid < 16) sdtb[tid] = dtb[d0 + tid];
    __syncthreads();
    for (int i = tid; i < 1024; i += 256) {
        int t = i >> 4, dl = i & 15;
        float acc = sdtb[dl];
#pragma unroll
        for (int r = 0; r < 6; ++r) acc += sxd[t * 40 + r] * sdtw[dl * 6 + r];
        sdt[i] = softplusf_(acc);
    }
    __syncthreads();
    const int s = tid & 15, dl = tid >> 4;
    const float Ads = -__expf(alog[(d0 + dl) * DS + s]);
    float h = hinit[((b * NCHUNK + ch) * DI + d0 + dl) * DS + s];
    for (int t = 0; t < 64; ++t) {
        float dtv = sdt[t * 16 + dl];
        float dA = __expf(dtv * Ads);
        h = dA * h + dtv * sxd[t * 40 + 6 + s] * sxi[t * 16 + dl];
        float p = h * sxd[t * 40 + 22 + s];
        p = dpp_add16_<0x128>(p);   // += row_ror:8
        p = dpp_add16_<0x124>(p);   // += row_ror:4
        p = dpp_add16_<0x122>(p);   // += row_ror:2
        p = dpp_add16_<0x121>(p);   // += row_ror:1  -> all 16 lanes hold sum
        if (s == 0) sy[t * 16 + dl] = p;
    }
    __syncthreads();
    for (int i = tid; i < 1024; i += 256) {
        int t = i >> 4, j = i & 15;
        float gate = siluf_(szs[i]);
        yg[(b * LQ + t0 + t) * DI + d0 + j] = (sy[i] + sxi[i] * Dp[d0 + j]) * gate;
    }
}

// ---------------- K7: out_proj GEMM, store transposed to NCHW xm[b,c,l] ----------------
// grid (L/64, 3, B)
__global__ __launch_bounds__(256) void k7_outproj(const float* __restrict__ yg,
    const float* __restrict__ wo, float* __restrict__ xm)
{
    const int l0 = blockIdx.x * 64;
    const int n0 = blockIdx.y * 32;
    const int b  = blockIdx.z;
    __shared__ float syT[96 * 68];    // [k(half)][l]
    __shared__ float wtT[192 * 36];   // [k][n]
    const int tid = threadIdx.x;
    for (int i = tid; i < 32 * 48; i += 256) {
        int n = i / 48, kq = i - n * 48;
        float4 v = *(const float4*)&wo[(n0 + n) * DI + kq * 4];
        wtT[(kq * 4 + 0) * 36 + n] = v.x;
        wtT[(kq * 4 + 1) * 36 + n] = v.y;
        wtT[(kq * 4 + 2) * 36 + n] = v.z;
        wtT[(kq * 4 + 3) * 36 + n] = v.w;
    }
    const int tx = tid & 15;   // l quad
    const int ty = tid >> 4;   // n pair
    float acc[2][4];
#pragma unroll
    for (int j = 0; j < 2; ++j)
#pragma unroll
        for (int i = 0; i < 4; ++i) acc[j][i] = 0.f;
    for (int half = 0; half < 2; ++half) {
        __syncthreads();
        for (int i = tid; i < 64 * 24; i += 256) {
            int l = i / 24, kq = i - l * 24;
            float4 v = *(const float4*)&yg[(b * LQ + l0 + l) * DI + half * 96 + kq * 4];
            syT[(kq * 4 + 0) * 68 + l] = v.x;
            syT[(kq * 4 + 1) * 68 + l] = v.y;
            syT[(kq * 4 + 2) * 68 + l] = v.z;
            syT[(kq * 4 + 3) * 68 + l] = v.w;
        }
        __syncthreads();
        for (int k = 0; k < 96; ++k) {
            float4 a = *(const float4*)&syT[k * 68 + tx * 4];
            int kk = half * 96 + k;
            float b0 = wtT[kk * 36 + ty * 2 + 0];
            float b1 = wtT[kk * 36 + ty * 2 + 1];
            acc[0][0] += a.x * b0; acc[0][1] += a.y * b0;
            acc[0][2] += a.z * b0; acc[0][3] += a.w * b0;
            acc[1][0] += a.x * b1; acc[1][1] += a.y * b1;
            acc[1][2] += a.z * b1; acc[1][3] += a.w * b1;
        }
    }
#pragma unroll
    for (int j = 0; j < 2; ++j) {
        float4 v = make_float4(acc[j][0], acc[j][1], acc[j][2], acc[j][3]);
        *(float4*)&xm[(b * 96 + n0 + ty * 2 + j) * LQ + l0 + tx * 4] = v;
    }
}

// ---------------- K8 v12: 3x3 conv partials — async global_load_lds + LDS dbuf ----------------
// Block 256 = 64 spatial (16 col-quads x 4 rows, 4px) x 4 wave-uniform co-quads.
// grid (6 co x 4 ks, 16 y, 4 b) = 1536 blocks (6/CU). Each block: 16 co, 24 ci (6 chunks of 4).
// Staging: __builtin_amdgcn_global_load_lds (NO dest VGPRs -> prefetch register state gone;
// r4-r11 all stalled at ~10% occupancy because register-held prefetch forced VGPR 100-236).
// LDS layout is slot-contiguous (slot i -> base + i*16B) = the wave-uniform-base + lane*size
// form the instruction requires; v11's DPP-halo made the input tile halo-free/contiguous.
// Double-buffered; ONE __syncthreads per chunk (drains vmcnt; loads for chunk+1 issued before
// compute of chunk -> ~1152 cyc FMA covers the load latency). Boundary rows pre-zeroed once
// in both buffers (mask chunk-invariant; masked lanes never overwrite).
#define K8_INQ 384              // staged float4 quads per chunk
#define K8_WNEL 576             // staged weight floats per chunk
__global__ __launch_bounds__(256) void k8_conv3(const float* __restrict__ xm,
    const float* __restrict__ w2, float* __restrict__ pbuf)
{
    const int ks  = blockIdx.x & 3;
    const int co0 = (blockIdx.x >> 2) * 16;
    const int y0  = blockIdx.y * 4;
    const int b   = blockIdx.z;
    __shared__ float sin2[2][1536];     // [buf][ci][row][64]
    __shared__ float swt2[2][576];      // [buf][ci][tap][16co]
    const int tid = threadIdx.x;
    const int sx = tid & 15;
    const int sy = (tid >> 4) & 3;
    const int cq = tid >> 6;            // wave id == wave-uniform co-quad

    // input slots: j=0 slot=tid (all), j=1 slot=256+tid (tid<128)
    int in_goff[2];
    bool in_ok[2];
#pragma unroll
    for (int j = 0; j < 2; ++j) {
        int i = tid + j * 256;
        int ci  = i / 96;
        int rem = i - ci * 96;
        int row = rem >> 4;
        int qx  = rem & 15;
        int gy  = y0 + row - 1;
        bool ok = (i < K8_INQ) && gy >= 0 && gy < 64;
        in_ok[j]  = ok;
        in_goff[j] = ok ? (ci * 4096 + gy * 64 + qx * 4) : 0;
    }
    // weight slots: j=0 slot=tid, j=1 slot=256+tid, j=2 slot=512+tid (tid<64)
    int w_goff[3];
#pragma unroll
    for (int j = 0; j < 3; ++j) {
        int i = tid + j * 256;
        int ci  = i / 144;
        int rem = i - ci * 144;
        int k   = rem >> 4;
        int cl  = rem & 15;
        w_goff[j] = (i < K8_WNEL) ? (cl * 864 + ci * 9 + k) : 0;
    }

    const float* xb = xm + (size_t)b * 96 * 4096 + (size_t)ks * 24 * 4096;
    const float* wb = w2 + (size_t)co0 * 864 + ks * 24 * 9;
    const float4 zero4 = make_float4(0.f, 0.f, 0.f, 0.f);

    // --- pre-zero boundary cells in BOTH buffers (chunk-invariant mask) ---
#pragma unroll
    for (int bu = 0; bu < 2; ++bu) {
        if (!in_ok[0]) *(float4*)&sin2[bu][tid * 4] = zero4;
        if (tid < 128 && !in_ok[1]) *(float4*)&sin2[bu][(256 + tid) * 4] = zero4;
    }

    // --- stage chunk 0 into buffer 0 (async) ---
    {
        const float* gx = xb;
        const float* gw = wb;
        if (in_ok[0]) async_g2l16_(gx + in_goff[0], &sin2[0][cq * 256]);
        if (tid < 128 && in_ok[1]) async_g2l16_(gx + in_goff[1], &sin2[0][1024 + cq * 256]);
        async_g2l4_(gw + w_goff[0], &swt2[0][cq * 64]);
        async_g2l4_(gw + w_goff[1], &swt2[0][256 + cq * 64]);
        if (tid < 64) async_g2l4_(gw + w_goff[2], &swt2[0][512 + cq * 64]);
    }
    __syncthreads();

    float acc[4][4];
#pragma unroll
    for (int c = 0; c < 4; ++c)
#pragma unroll
        for (int x = 0; x < 4; ++x) acc[c][x] = 0.f;

#pragma clang loop unroll(disable)
    for (int ch = 0; ch < 6; ++ch) {
        // issue async loads for next chunk into the other buffer (no dest regs)
        if (ch < 5) {
            const int nb = (ch + 1) & 1;
            const float* gx = xb + (ch + 1) * 16384;
            const float* gw = wb + (ch + 1) * 36;
            if (in_ok[0]) async_g2l16_(gx + in_goff[0], &sin2[nb][cq * 256]);
            if (tid < 128 && in_ok[1]) async_g2l16_(gx + in_goff[1], &sin2[nb][1024 + cq * 256]);
            async_g2l4_(gw + w_goff[0], &swt2[nb][cq * 64]);
            async_g2l4_(gw + w_goff[1], &swt2[nb][256 + cq * 64]);
            if (tid < 64) async_g2l4_(gw + w_goff[2], &swt2[nb][512 + cq * 64]);
        }

        // compute on current buffer
        const float* sc = sin2[ch & 1];
        const float* wc = swt2[ch & 1];
#pragma unroll
        for (int cii = 0; cii < 4; ++cii) {
            float w6[3][6];
#pragma unroll
            for (int r = 0; r < 3; ++r) {
                float4 v = *(const float4*)&sc[(cii * 6 + sy + r) * 64 + sx * 4];
                w6[r][0] = dpp_shift_<0x111>(v.w);   // row_shr:1 -> col 4sx-1 (0 at sx=0)
                w6[r][1] = v.x; w6[r][2] = v.y; w6[r][3] = v.z; w6[r][4] = v.w;
                w6[r][5] = dpp_shift_<0x101>(v.x);   // row_shl:1 -> col 4sx+4 (0 at sx=15)
            }
#pragma unroll
            for (int ky = 0; ky < 3; ++ky) {
#pragma unroll
                for (int kx = 0; kx < 3; ++kx) {
                    float4 wv = *(const float4*)&wc[(cii * 9 + ky * 3 + kx) * 16 + cq * 4];
#pragma unroll
                    for (int x = 0; x < 4; ++x) {
                        float pv = w6[ky][x + kx];
                        acc[0][x] = fmaf(pv, wv.x, acc[0][x]);
                        acc[1][x] = fmaf(pv, wv.y, acc[1][x]);
                        acc[2][x] = fmaf(pv, wv.z, acc[2][x]);
                        acc[3][x] = fmaf(pv, wv.w, acc[3][x]);
                    }
                }
            }
        }

        // one barrier: drains vmcnt (next buffer ready) + protects buffer reuse
        __syncthreads();
    }

    // --- store fp32 partials: pbuf[ks][b][co][y][x] ---
    const int yy = y0 + sy;
    float* pb = pbuf + (size_t)ks * 1572864;
#pragma unroll
    for (int c = 0; c < 4; ++c) {
        const int cc = co0 + cq * 4 + c;
        float4 o = make_float4(acc[c][0], acc[c][1], acc[c][2], acc[c][3]);
        *(float4*)&pb[((size_t)(b * 96 + cc) * 64 + yy) * 64 + sx * 4] = o;
    }
}

// ---------------- K9: reduce 4 partials + BN + ReLU6 ----------------
// grid 1536, block 256; thread = 4 consecutive px (same channel).
__global__ __launch_bounds__(256) void k9_reduce(const float* __restrict__ pbuf,
    const float* __restrict__ bng, const float* __restrict__ bnb,
    const float* __restrict__ bnm, const float* __restrict__ bnv,
    float* __restrict__ out)
{
    const int q = blockIdx.x * 256 + threadIdx.x;   // quad index, 393216 total
    const int idx = q * 4;
    const int c = (idx >> 12) % 96;
    float4 s = *(const float4*)&pbuf[idx];
    float4 s1 = *(const float4*)&pbuf[idx + 1572864];
    float4 s2 = *(const float4*)&pbuf[idx + 2 * 1572864];
    float4 s3 = *(const float4*)&pbuf[idx + 3 * 1572864];
    s.x += s1.x + s2.x + s3.x;
    s.y += s1.y + s2.y + s3.y;
    s.z += s1.z + s2.z + s3.z;
    s.w += s1.w + s2.w + s3.w;
    float inv = bng[c] / sqrtf(bnv[c] + 1e-5f);
    float add = bnb[c] - bnm[c] * inv;
    float4 o;
    o.x = fminf(fmaxf(s.x * inv + add, 0.f), 6.f);
    o.y = fminf(fmaxf(s.y * inv + add, 0.f), 6.f);
    o.z = fminf(fmaxf(s.z * inv + add, 0.f), 6.f);
    o.w = fminf(fmaxf(s.w * inv + add, 0.f), 6.f);
    *(float4*)&out[idx] = o;
}

extern "C" void kernel_launch(void* const* d_in, const int* in_sizes, int n_in,
                              void* d_out, int out_size, void* d_ws, size_t ws_size,
                              hipStream_t stream) {
    (void)in_sizes; (void)n_in; (void)out_size; (void)ws_size;
    const float* x    = (const float*)d_in[0];
    const float* w_in = (const float*)d_in[1];
    const float* cw   = (const float*)d_in[2];
    const float* cb   = (const float*)d_in[3];
    const float* xw   = (const float*)d_in[4];
    const float* dtw  = (const float*)d_in[5];
    const float* dtb  = (const float*)d_in[6];
    const float* alog = (const float*)d_in[7];
    const float* Dp   = (const float*)d_in[8];
    const float* wo   = (const float*)d_in[9];
    const float* w2   = (const float*)d_in[10];
    const float* bng  = (const float*)d_in[11];
    const float* bnb  = (const float*)d_in[12];
    const float* bnm  = (const float*)d_in[13];
    const float* bnv  = (const float*)d_in[14];

    float* ws = (float*)d_ws;
    float* xi_raw = ws;                    // 3,145,728 (reused as yg after K2, pbuf after K7)
    float* z      = ws + 3145728;          // 3,145,728 (pbuf tail after K6)
    float* xi     = ws + 6291456;          // 3,145,728
    float* xdbl   = ws + 9437184;          //   622,592
    float* cA     = ws + 10059776;         //   786,432
    float* cB     = ws + 10846208;         //   786,432
    float* hinit  = ws + 11632640;         //   786,432
    float* xm     = ws + 12419072;         // 1,572,864   (total 13,991,936 floats = 56 MB)
    float* yg     = xi_raw;
    float* pbuf   = xi_raw;                // 4 x 1,572,864 = 6,291,456 floats (xi_raw + z)

    dim3 blk(256);
    k1_inproj<<<dim3(64, 6, 4), blk, 0, stream>>>(x, w_in, xi_raw, z);
    k2_conv1d<<<dim3(12288), blk, 0, stream>>>(xi_raw, cw, cb, xi);
    k3_xdbl<<<dim3(64, 4), blk, 0, stream>>>(xi, xw, xdbl);
    k4_scanA<<<dim3(NCHUNK, 12, 4), blk, 0, stream>>>(xdbl, xi, dtw, dtb, alog, cA, cB);
    k5_combine<<<dim3(48), blk, 0, stream>>>(cA, cB, hinit);
    k6_scanC<<<dim3(NCHUNK, 12, 4), blk, 0, stream>>>(xdbl, xi, z, dtw, dtb, alog, Dp, hinit, yg);
    k7_outproj<<<dim3(64, 3, 4), blk, 0, stream>>>(yg, wo, xm);
    k8_conv3<<<dim3(24, 16, 4), blk, 0, stream>>>(xm, w2, pbuf);
    k9_reduce<<<dim3(1536), blk, 0, stream>>>(pbuf, bng, bnb, bnm, bnv, (float*)d_out);
}